// Round 5
// baseline (1092.505 us; speedup 1.0000x reference)
//
#include <hip/hip_runtime.h>
#include <cstdint>
#include <cstddef>

#define NNODES 10000
#define HDIM 64
#define INDIM 128
#define TSTEPS 50

#define YB4N 160016u   /* (NNODES+1)*HDIM/4 uint4s in yb table */
#define YCHUNK 2026u   /* ceil(YB4N/79) -- 79 slices (blocks>>3), one table copy per XCD */

__device__ __forceinline__ float sigmoidf_(float x){ return 1.0f/(1.0f+__expf(-x)); }
__device__ __forceinline__ float tanhf_(float x){ float e=__expf(2.0f*x); return 1.0f-2.0f/(e+1.0f); }

__device__ __forceinline__ uint32_t pack_bf16x2(float a, float b){
  uint32_t ua = __float_as_uint(a), ub = __float_as_uint(b);
  ua = (ua + 0x7fffu + ((ua>>16)&1u)) >> 16;          // rne
  ub = (ub + 0x7fffu + ((ub>>16)&1u)) >> 16;
  return ua | (ub<<16);
}

__global__ void hist_kernel(const int* __restrict__ src, const int* __restrict__ dst,
                            int* __restrict__ deg_out, int* __restrict__ deg_in, int E){
  int e = blockIdx.x*blockDim.x + threadIdx.x;
  if (e < E){
    atomicAdd(&deg_out[src[e]], 1);
    atomicAdd(&deg_in[dst[e]], 1);
  }
}

// row_off uses degrees PADDED to multiples of 8 (branch-free 8-unroll gather)
__global__ void scan_kernel(const int* __restrict__ deg_in, const int* __restrict__ deg_out,
                            int* __restrict__ row_off, int* __restrict__ cursor,
                            float* __restrict__ norm_s, float* __restrict__ norm_d){
  __shared__ int part[256];
  int tid = threadIdx.x;
  const int CH = (NNODES + 255)/256;   // 40
  int base = tid*CH;
  int local = 0;
  for (int k=0;k<CH;k++){ int n=base+k; if(n<NNODES) local += (deg_in[n]+7)&~7; }
  part[tid]=local;
  __syncthreads();
  if (tid==0){
    int run=0;
    for(int i=0;i<256;i++){ int t=part[i]; part[i]=run; run+=t; }
  }
  __syncthreads();
  int run = part[tid];
  for (int k=0;k<CH;k++){
    int n=base+k;
    if (n<NNODES){
      int di = deg_in[n];
      row_off[n]=run; cursor[n]=run;
      run += (di+7)&~7;
      norm_d[n] = rsqrtf(fmaxf((float)di,1.0f));
      norm_s[n] = rsqrtf(fmaxf((float)deg_out[n],1.0f));
    }
  }
  if (tid==255) row_off[NNODES]=run;   // padded E
}

// csr stores BYTE offsets into the yb table (src*256); sentinel row NNODES stays zero
__global__ void fill_kernel(const int* __restrict__ src, const int* __restrict__ dst,
                            int* __restrict__ cursor, uint32_t* __restrict__ csrb, int E){
  int e = blockIdx.x*blockDim.x + threadIdx.x;
  if (e<E){
    int pos = atomicAdd(&cursor[dst[e]],1);
    csrb[pos] = (uint32_t)src[e]*256u;
  }
}

__global__ void pad_kernel(const int* __restrict__ row_off, const int* __restrict__ cursor,
                           uint32_t* __restrict__ csrb){
  int n = blockIdx.x*blockDim.x + threadIdx.x;
  if (n < NNODES){
    int q  = cursor[n];
    int qe = row_off[n+1];
    for (; q < qe; ++q) csrb[q] = (uint32_t)NNODES*256u;   // zero sentinel row
  }
}

__global__ void xproj_kernel(const float* __restrict__ x,
                             const float* __restrict__ wr, const float* __restrict__ br,
                             const float* __restrict__ wz, const float* __restrict__ bz,
                             const float* __restrict__ wh, const float* __restrict__ bh,
                             float* __restrict__ xproj){
  int tid = threadIdx.x;             // 0..383
  if (tid >= 384) return;
  int g = tid >> 7; int r = tid & 127; int b = r >> 6; int i = r & 63;
  const float* w  = (g==0)?wr:(g==1)?wz:wh;
  const float* bb = (g==0)?br:(g==1)?bz:bh;
  float s = bb[i];
  for (int k=0;k<INDIM;k++) s = fmaf(x[b*INDIM+k], w[k*HDIM+i], s);
  xproj[g*128 + i*2 + b] = s;
}

__global__ void transpose_w_kernel(const float* __restrict__ gcn_w, float* __restrict__ wT){
  int tid = threadIdx.x;
  for (int k=0;k<16;k++){
    int idx = tid*16 + k;
    int i = idx >> 6, j = idx & 63;       // wT[i][j] = W[j][i]
    wT[idx] = gcn_w[j*HDIM + i];
  }
}

#define ACC8(A0,A1,A2,A3,q0,q1,q2,q3,q4,q5,q6,q7) do{ \
  A0.x += __uint_as_float((q0)<<16); A0.y += __uint_as_float((q0)&0xffff0000u); \
  A1.x += __uint_as_float((q1)<<16); A1.y += __uint_as_float((q1)&0xffff0000u); \
  A2.x += __uint_as_float((q2)<<16); A2.y += __uint_as_float((q2)&0xffff0000u); \
  A3.x += __uint_as_float((q3)<<16); A3.y += __uint_as_float((q3)&0xffff0000u); \
  A0.x += __uint_as_float((q4)<<16); A0.y += __uint_as_float((q4)&0xffff0000u); \
  A1.x += __uint_as_float((q5)<<16); A1.y += __uint_as_float((q5)&0xffff0000u); \
  A2.x += __uint_as_float((q6)<<16); A2.y += __uint_as_float((q6)&0xffff0000u); \
  A3.x += __uint_as_float((q7)<<16); A3.y += __uint_as_float((q7)&0xffff0000u); \
}while(0)

#define GATHER8(cp,it,P0,P1,P2,P3,P4,P5,P6,P7) \
  uint4 oa##P0 = (cp)[2*(it)], ob##P0 = (cp)[2*(it)+1]; \
  uint32_t P0 = *(const uint32_t*)(ybb+oa##P0.x); \
  uint32_t P1 = *(const uint32_t*)(ybb+oa##P0.y); \
  uint32_t P2 = *(const uint32_t*)(ybb+oa##P0.z); \
  uint32_t P3 = *(const uint32_t*)(ybb+oa##P0.w); \
  uint32_t P4 = *(const uint32_t*)(ybb+ob##P0.x); \
  uint32_t P5 = *(const uint32_t*)(ybb+ob##P0.y); \
  uint32_t P6 = *(const uint32_t*)(ybb+ob##P0.z); \
  uint32_t P7 = *(const uint32_t*)(ybb+ob##P0.w);

// One wave handles nodes {wid, wid+5000}. 625 blocks, all resident (3/CU).
// Kernel-boundary L2 invalidation makes every step's gathers first-touch-miss;
// so: (1) blocks sharing an XCD stripe-stream the yb+csr tables into L2 up front,
// (2) all once-used state traffic is nontemporal so it can't evict the warm tables.
__launch_bounds__(512, 6)
__global__ void step_kernel(const float2* __restrict__ h_in, float2* __restrict__ h_out,
                            const uint32_t* __restrict__ yb_in, uint32_t* __restrict__ yb_out,
                            float* __restrict__ out, int t,
                            const int* __restrict__ row_off, const uint32_t* __restrict__ csrb,
                            const float* __restrict__ norm_d, const float* __restrict__ norm_s,
                            const float* __restrict__ wT, const float* __restrict__ gcn_b,
                            const float2* __restrict__ xproj,
                            uint32_t cn4, uint32_t cchunk){
  __shared__ __align__(16) float4 wlds[64][16];      // 16 KB swizzled W
  __shared__ __align__(16) float2 hstage[8][2][64];  // 8 KB wave-private

  const int tid  = threadIdx.x;
  const int lane = tid & 63;
  const int wv   = tid >> 6;

  // ---- L2 warm: stripe-stream yb + csr (blockIdx%8 ~ XCD, round-robin dispatch) ----
  uint32_t pf_keep = 0;
  {
    const uint32_t s = (uint32_t)blockIdx.x >> 3;    // 0..78
    const uint4* yb4 = (const uint4*)yb_in;
    uint32_t jb = s*YCHUNK, je = jb + YCHUNK; if (je > YB4N) je = YB4N;
    #pragma unroll
    for (int i=0;i<4;i++){
      uint32_t j = jb + (uint32_t)tid + (uint32_t)i*512u;
      if (j < je){ uint4 v = yb4[j]; pf_keep ^= v.x ^ v.y ^ v.z ^ v.w; }
    }
    const uint4* cb4 = (const uint4*)csrb;
    uint32_t cb = s*cchunk, ce = cb + cchunk; if (ce > cn4) ce = cn4;
    #pragma unroll
    for (int i=0;i<2;i++){
      uint32_t j = cb + (uint32_t)tid + (uint32_t)i*512u;
      if (j < ce){ uint4 v = cb4[j]; pf_keep ^= v.x ^ v.y ^ v.z ^ v.w; }
    }
  }

  // stage W into LDS (ds_writes only; barrier comes after the gather phase)
  {
    const float4* wt4 = (const float4*)wT;
    #pragma unroll
    for (int q=0;q<2;q++){
      int c = tid*2 + q;
      int l = c >> 4, kk = c & 15;
      int swl = (l & 15) ^ (((l>>4)&1) << 2);
      wlds[l][kk ^ swl] = wt4[c];
    }
  }

  const int wid = __builtin_amdgcn_readfirstlane(blockIdx.x*8 + wv);  // 0..4999
  const int n0 = wid, n1 = wid + 5000;

  int beg0 = __builtin_amdgcn_readfirstlane(row_off[n0]);
  int end0 = __builtin_amdgcn_readfirstlane(row_off[n0+1]);
  int beg1 = __builtin_amdgcn_readfirstlane(row_off[n1]);
  int end1 = __builtin_amdgcn_readfirstlane(row_off[n1+1]);

  // h state: read-once -> nontemporal (no L2 allocation)
  uint64_t hv0 = __builtin_nontemporal_load((const unsigned long long*)h_in + (size_t)n0*HDIM + lane);
  uint64_t hv1 = __builtin_nontemporal_load((const unsigned long long*)h_in + (size_t)n1*HDIM + lane);

  const char* ybb = (const char*)yb_in + (uint32_t)(lane*4);
  const uint4* cp0 = (const uint4*)(csrb + beg0);    // beg%8==0 -> 16B aligned
  const uint4* cp1 = (const uint4*)(csrb + beg1);
  const int it0 = (end0-beg0)>>3;
  const int it1 = (end1-beg1)>>3;
  const int itc = it0 < it1 ? it0 : it1;

  float2 A0{0.f,0.f},A1{0.f,0.f},A2{0.f,0.f},A3{0.f,0.f};   // node0
  float2 B0{0.f,0.f},B1{0.f,0.f},B2{0.f,0.f},B3{0.f,0.f};   // node1

  int it = 0;
  #pragma unroll 1
  for (; it<itc; ++it){            // common loop: 16 gathers in flight
    GATHER8(cp0,it,p0,p1,p2,p3,p4,p5,p6,p7);
    GATHER8(cp1,it,q0,q1,q2,q3,q4,q5,q6,q7);
    ACC8(A0,A1,A2,A3,p0,p1,p2,p3,p4,p5,p6,p7);
    ACC8(B0,B1,B2,B3,q0,q1,q2,q3,q4,q5,q6,q7);
  }
  #pragma unroll 1
  for (int ia=it; ia<it0; ++ia){   // node0 tail
    GATHER8(cp0,ia,p0,p1,p2,p3,p4,p5,p6,p7);
    ACC8(A0,A1,A2,A3,p0,p1,p2,p3,p4,p5,p6,p7);
  }
  #pragma unroll 1
  for (int ib=it; ib<it1; ++ib){   // node1 tail
    GATHER8(cp1,ib,q0,q1,q2,q3,q4,q5,q6,q7);
    ACC8(B0,B1,B2,B3,q0,q1,q2,q3,q4,q5,q6,q7);
  }

  __asm__ volatile("" :: "v"(pf_keep));   // keep prefetch loads alive

  float s00 = (A0.x+A1.x)+(A2.x+A3.x), s01 = (A0.y+A1.y)+(A2.y+A3.y);
  float s10 = (B0.x+B1.x)+(B2.x+B3.x), s11 = (B0.y+B1.y)+(B2.y+B3.y);

  const float  bias = gcn_b[lane];
  const float2 xrv  = xproj[lane];
  const float2 xzv  = xproj[64+lane];
  const float2 xhv  = xproj[128+lane];
  const float  nd0  = norm_d[n0], ns0 = norm_s[n0];
  const float  nd1  = norm_d[n1], ns1 = norm_s[n1];

  float2 hold0 = make_float2(__uint_as_float((uint32_t)hv0), __uint_as_float((uint32_t)(hv0>>32)));
  float2 hold1 = make_float2(__uint_as_float((uint32_t)hv1), __uint_as_float((uint32_t)(hv1>>32)));

  float g00 = fmaf(nd0, s00, bias), g01 = fmaf(nd0, s01, bias);
  float g10 = fmaf(nd1, s10, bias), g11 = fmaf(nd1, s11, bias);

  float r00 = sigmoidf_(xrv.x+g00), r01 = sigmoidf_(xrv.y+g01);
  float r10 = sigmoidf_(xrv.x+g10), r11 = sigmoidf_(xrv.y+g11);
  float z00 = sigmoidf_(xzv.x+g00), z01 = sigmoidf_(xzv.y+g01);
  float z10 = sigmoidf_(xzv.x+g10), z11 = sigmoidf_(xzv.y+g11);
  float t00 = tanhf_(xhv.x+r00*g00), t01 = tanhf_(xhv.y+r01*g01);
  float t10 = tanhf_(xhv.x+r10*g10), t11 = tanhf_(xhv.y+r11*g11);
  float h00 = hold0.x + z00*(t00 - hold0.x);
  float h01 = hold0.y + z01*(t01 - hold0.y);
  float h10 = hold1.x + z10*(t10 - hold1.x);
  float h11 = hold1.y + z11*(t11 - hold1.y);

  // all state writes nontemporal: next-step reads cross the L2-invalidating kernel
  // boundary anyway, and cached writes would evict the warmed yb table.
  const size_t NH = (size_t)NNODES*HDIM;
  uint64_t w0 = (uint64_t)__float_as_uint(h00) | ((uint64_t)__float_as_uint(h01)<<32);
  uint64_t w1 = (uint64_t)__float_as_uint(h10) | ((uint64_t)__float_as_uint(h11)<<32);
  __builtin_nontemporal_store(w0, (unsigned long long*)h_out + (size_t)n0*HDIM + lane);
  __builtin_nontemporal_store(w1, (unsigned long long*)h_out + (size_t)n1*HDIM + lane);
  size_t idx0 = (size_t)t*NH + (size_t)n0*HDIM + lane;
  size_t idx1 = (size_t)t*NH + (size_t)n1*HDIM + lane;
  __builtin_nontemporal_store(h00, &out[idx0]);
  __builtin_nontemporal_store(h01, &out[(size_t)TSTEPS*NH + idx0]);
  __builtin_nontemporal_store(h10, &out[idx1]);
  __builtin_nontemporal_store(h11, &out[(size_t)TSTEPS*NH + idx1]);

  hstage[wv][0][lane] = make_float2(h00,h01);
  hstage[wv][1][lane] = make_float2(h10,h11);
  __syncthreads();   // wlds ready (and our hstage writes drained)

  // y_new = h_new @ W for both nodes (dual chains, broadcast h + per-lane W column)
  const int sl = (lane & 15) ^ (((lane>>4)&1) << 2);
  const float4* hp0 = (const float4*)hstage[wv][0];
  const float4* hp1 = (const float4*)hstage[wv][1];
  float y00=0.f, y01=0.f, y10=0.f, y11=0.f;
  #pragma unroll
  for (int kk=0;kk<16;kk++){
    float4 w4  = wlds[lane][kk ^ sl];
    float4 ha0 = hp0[2*kk], hb0 = hp0[2*kk+1];
    float4 ha1 = hp1[2*kk], hb1 = hp1[2*kk+1];
    y00 = fmaf(w4.x, ha0.x, y00); y01 = fmaf(w4.x, ha0.y, y01);
    y10 = fmaf(w4.x, ha1.x, y10); y11 = fmaf(w4.x, ha1.y, y11);
    y00 = fmaf(w4.y, ha0.z, y00); y01 = fmaf(w4.y, ha0.w, y01);
    y10 = fmaf(w4.y, ha1.z, y10); y11 = fmaf(w4.y, ha1.w, y11);
    y00 = fmaf(w4.z, hb0.x, y00); y01 = fmaf(w4.z, hb0.y, y01);
    y10 = fmaf(w4.z, hb1.x, y10); y11 = fmaf(w4.z, hb1.y, y11);
    y00 = fmaf(w4.w, hb0.z, y00); y01 = fmaf(w4.w, hb0.w, y01);
    y10 = fmaf(w4.w, hb1.z, y10); y11 = fmaf(w4.w, hb1.w, y11);
  }
  __builtin_nontemporal_store(pack_bf16x2(ns0*y00, ns0*y01), yb_out + (uint32_t)n0*HDIM + lane);
  __builtin_nontemporal_store(pack_bf16x2(ns1*y10, ns1*y11), yb_out + (uint32_t)n1*HDIM + lane);
}

extern "C" void kernel_launch(void* const* d_in, const int* in_sizes, int n_in,
                              void* d_out, int out_size, void* d_ws, size_t ws_size,
                              hipStream_t stream){
  const float* x   = (const float*)d_in[0];
  const int*   src = (const int*)d_in[1];
  const int*   dst = (const int*)d_in[2];
  const float* wr  = (const float*)d_in[3];
  const float* br  = (const float*)d_in[4];
  const float* wz  = (const float*)d_in[5];
  const float* bz  = (const float*)d_in[6];
  const float* wh  = (const float*)d_in[7];
  const float* bh  = (const float*)d_in[8];
  const float* gw  = (const float*)d_in[9];
  const float* gb  = (const float*)d_in[10];
  float* out = (float*)d_out;
  const int E = in_sizes[1];

  char* ws = (char*)d_ws;
  size_t o = 0;
  int*   deg_out = (int*)(ws+o);  o += 10240*4;
  int*   deg_in  = (int*)(ws+o);  o += 10240*4;
  int*   cursor  = (int*)(ws+o);  o += 10240*4;
  int*   row_off = (int*)(ws+o);  o += 10256*4;
  float* norm_s  = (float*)(ws+o); o += 10240*4;
  float* norm_d  = (float*)(ws+o); o += 10240*4;
  const size_t CSRCAP = (size_t)E + 7*NNODES + 16;
  uint32_t* csrb = (uint32_t*)(ws+o);  o += ((CSRCAP*4 + 15) & ~(size_t)15);
  float* xproj   = (float*)(ws+o); o += 512*4;
  float* wT      = (float*)(ws+o); o += 4096*4;
  o = (o + 255) & ~(size_t)255;
  const size_t NHf2 = (size_t)NNODES*HDIM*sizeof(float2);        // 5.12 MB
  const size_t NYB  = (size_t)(NNODES+1)*HDIM*sizeof(uint32_t);  // 2.56 MB (+sentinel)
  uint32_t* yb0 = (uint32_t*)(ws+o); o += NYB;   // yb0,yb1,h0 contiguous -> one memset
  uint32_t* yb1 = (uint32_t*)(ws+o); o += NYB;
  float2*   h0  = (float2*)(ws+o);   o += NHf2;
  float2*   h1  = (float2*)(ws+o);   o += NHf2;  // fully written before first read

  hipMemsetAsync(deg_out, 0, 2*10240*4, stream);
  hipMemsetAsync(yb0, 0, 2*NYB + NHf2, stream);  // zeros yb0, yb1 (sentinels), h0

  int eb = (E+255)/256;
  hist_kernel<<<eb,256,0,stream>>>(src,dst,deg_out,deg_in,E);
  scan_kernel<<<1,256,0,stream>>>(deg_in,deg_out,row_off,cursor,norm_s,norm_d);
  fill_kernel<<<eb,256,0,stream>>>(src,dst,cursor,csrb,E);
  pad_kernel<<<(NNODES+255)/256,256,0,stream>>>(row_off,cursor,csrb);
  xproj_kernel<<<1,384,0,stream>>>(x,wr,br,wz,bz,wh,bh,xproj);
  transpose_w_kernel<<<1,256,0,stream>>>(gw,wT);

  const uint32_t cn4    = (uint32_t)(CSRCAP/4);       // uint4s in csr region
  const uint32_t cchunk = (cn4 + 78u)/79u;            // per-slice stripe

  float2* hin = h0;  float2* hout = h1;
  uint32_t* ybin = yb0; uint32_t* ybout = yb1;
  for (int t=0;t<TSTEPS;t++){
    step_kernel<<<625,512,0,stream>>>(hin,hout,ybin,ybout,out,t,row_off,csrb,
                                      norm_d,norm_s,wT,gb,(const float2*)xproj,
                                      cn4,cchunk);
    float2* tf = hin; hin = hout; hout = tf;
    uint32_t* tb = ybin; ybin = ybout; ybout = tb;
  }
}

// Round 6
// 968.844 us; speedup vs baseline: 1.1276x; 1.1276x over previous
//
#include <hip/hip_runtime.h>
#include <cstdint>
#include <cstddef>

#define NNODES 10000
#define HDIM 64
#define INDIM 128
#define TSTEPS 50
#define SENTOFF ((uint32_t)NNODES*256u)

__device__ __forceinline__ float sigmoidf_(float x){ return 1.0f/(1.0f+__expf(-x)); }
__device__ __forceinline__ float tanhf_(float x){ float e=__expf(2.0f*x); return 1.0f-2.0f/(e+1.0f); }

__device__ __forceinline__ uint32_t pack_bf16x2(float a, float b){
  uint32_t ua = __float_as_uint(a), ub = __float_as_uint(b);
  ua = (ua + 0x7fffu + ((ua>>16)&1u)) >> 16;          // rne
  ub = (ub + 0x7fffu + ((ub>>16)&1u)) >> 16;
  return ua | (ub<<16);
}

__global__ void hist_kernel(const int* __restrict__ src, const int* __restrict__ dst,
                            int* __restrict__ deg_out, int* __restrict__ deg_in, int E){
  int e = blockIdx.x*blockDim.x + threadIdx.x;
  if (e < E){
    atomicAdd(&deg_out[src[e]], 1);
    atomicAdd(&deg_in[dst[e]], 1);
  }
}

// row_off uses degrees PADDED to multiples of 8
__global__ void scan_kernel(const int* __restrict__ deg_in, const int* __restrict__ deg_out,
                            int* __restrict__ row_off, int* __restrict__ cursor,
                            float* __restrict__ norm_s, float* __restrict__ norm_d){
  __shared__ int part[256];
  int tid = threadIdx.x;
  const int CH = (NNODES + 255)/256;   // 40
  int base = tid*CH;
  int local = 0;
  for (int k=0;k<CH;k++){ int n=base+k; if(n<NNODES) local += (deg_in[n]+7)&~7; }
  part[tid]=local;
  __syncthreads();
  if (tid==0){
    int run=0;
    for(int i=0;i<256;i++){ int t=part[i]; part[i]=run; run+=t; }
  }
  __syncthreads();
  int run = part[tid];
  for (int k=0;k<CH;k++){
    int n=base+k;
    if (n<NNODES){
      int di = deg_in[n];
      row_off[n]=run; cursor[n]=run;
      run += (di+7)&~7;
      norm_d[n] = rsqrtf(fmaxf((float)di,1.0f));
      norm_s[n] = rsqrtf(fmaxf((float)deg_out[n],1.0f));
    }
  }
  if (tid==255) row_off[NNODES]=run;   // padded E
}

// csr stores BYTE offsets into the yb table (src*256); sentinel row NNODES stays zero
__global__ void fill_kernel(const int* __restrict__ src, const int* __restrict__ dst,
                            int* __restrict__ cursor, uint32_t* __restrict__ csrb, int E){
  int e = blockIdx.x*blockDim.x + threadIdx.x;
  if (e<E){
    int pos = atomicAdd(&cursor[dst[e]],1);
    csrb[pos] = (uint32_t)src[e]*256u;
  }
}

__global__ void pad_kernel(const int* __restrict__ row_off, const int* __restrict__ cursor,
                           uint32_t* __restrict__ csrb){
  int n = blockIdx.x*blockDim.x + threadIdx.x;
  if (n < NNODES){
    int q  = cursor[n];
    int qe = row_off[n+1];
    for (; q < qe; ++q) csrb[q] = SENTOFF;
  }
}

// dense [N][32] offset table (fixed trip count gather); ovc[n] = #8-groups beyond 32
__global__ void dense_kernel(const int* __restrict__ row_off, const uint32_t* __restrict__ csrb,
                             uint32_t* __restrict__ csrd, uint32_t* __restrict__ ovc){
  int idx = blockIdx.x*blockDim.x + threadIdx.x;    // 0..319999
  if (idx >= NNODES*32) return;
  int n = idx >> 5, j = idx & 31;
  int beg = row_off[n], end = row_off[n+1];
  int pd = end - beg;                               // padded degree (multiple of 8)
  csrd[idx] = (j < pd) ? csrb[beg+j] : SENTOFF;
  if (j==0) ovc[n] = (pd > 32) ? (uint32_t)((pd-32)>>3) : 0u;
}

__global__ void xproj_kernel(const float* __restrict__ x,
                             const float* __restrict__ wr, const float* __restrict__ br,
                             const float* __restrict__ wz, const float* __restrict__ bz,
                             const float* __restrict__ wh, const float* __restrict__ bh,
                             float* __restrict__ xproj){
  int tid = threadIdx.x;             // 0..383
  if (tid >= 384) return;
  int g = tid >> 7; int r = tid & 127; int b = r >> 6; int i = r & 63;
  const float* w  = (g==0)?wr:(g==1)?wz:wh;
  const float* bb = (g==0)?br:(g==1)?bz:bh;
  float s = bb[i];
  for (int k=0;k<INDIM;k++) s = fmaf(x[b*INDIM+k], w[k*HDIM+i], s);
  xproj[g*128 + i*2 + b] = s;
}

__global__ void transpose_w_kernel(const float* __restrict__ gcn_w, float* __restrict__ wT){
  int tid = threadIdx.x;
  for (int k=0;k<16;k++){
    int idx = tid*16 + k;
    int i = idx >> 6, j = idx & 63;       // wT[i][j] = W[j][i]
    wT[idx] = gcn_w[j*HDIM + i];
  }
}

#define ACC8(A0,A1,A2,A3,q0,q1,q2,q3,q4,q5,q6,q7) do{ \
  A0.x += __uint_as_float((q0)<<16); A0.y += __uint_as_float((q0)&0xffff0000u); \
  A1.x += __uint_as_float((q1)<<16); A1.y += __uint_as_float((q1)&0xffff0000u); \
  A2.x += __uint_as_float((q2)<<16); A2.y += __uint_as_float((q2)&0xffff0000u); \
  A3.x += __uint_as_float((q3)<<16); A3.y += __uint_as_float((q3)&0xffff0000u); \
  A0.x += __uint_as_float((q4)<<16); A0.y += __uint_as_float((q4)&0xffff0000u); \
  A1.x += __uint_as_float((q5)<<16); A1.y += __uint_as_float((q5)&0xffff0000u); \
  A2.x += __uint_as_float((q6)<<16); A2.y += __uint_as_float((q6)&0xffff0000u); \
  A3.x += __uint_as_float((q7)<<16); A3.y += __uint_as_float((q7)&0xffff0000u); \
}while(0)

#define GATHER8(cp,it,P0,P1,P2,P3,P4,P5,P6,P7) \
  uint4 oa##P0 = (cp)[2*(it)], ob##P0 = (cp)[2*(it)+1]; \
  uint32_t P0 = *(const uint32_t*)(ybb+oa##P0.x); \
  uint32_t P1 = *(const uint32_t*)(ybb+oa##P0.y); \
  uint32_t P2 = *(const uint32_t*)(ybb+oa##P0.z); \
  uint32_t P3 = *(const uint32_t*)(ybb+oa##P0.w); \
  uint32_t P4 = *(const uint32_t*)(ybb+ob##P0.x); \
  uint32_t P5 = *(const uint32_t*)(ybb+ob##P0.y); \
  uint32_t P6 = *(const uint32_t*)(ybb+ob##P0.z); \
  uint32_t P7 = *(const uint32_t*)(ybb+ob##P0.w);

// One wave per node, 1250 blocks. Straight-line gather: 8 offset-vector loads
// (addresses known from n alone) -> 32 gathers all in flight -> one ACC block.
// No row_off dependency, no loop-carried vmcnt(0) drains.
__launch_bounds__(512, 6)
__global__ void step_kernel(const float2* __restrict__ h_in, float2* __restrict__ h_out,
                            const uint32_t* __restrict__ yb_in, uint32_t* __restrict__ yb_out,
                            float* __restrict__ out, int t,
                            const uint32_t* __restrict__ csrd, const uint32_t* __restrict__ ovc,
                            const int* __restrict__ row_off, const uint32_t* __restrict__ csrb,
                            const float* __restrict__ norm_d, const float* __restrict__ norm_s,
                            const float* __restrict__ wT, const float* __restrict__ gcn_b,
                            const float2* __restrict__ xproj){
  __shared__ __align__(16) float4 wlds[64][16];   // 16 KB swizzled W
  __shared__ __align__(16) float2 hstage[8][64];  // 4 KB wave-private

  const int tid  = threadIdx.x;
  const int lane = tid & 63;
  const int wv   = tid >> 6;

  // stage W into LDS (barrier deferred to after the gather+GRU phase)
  {
    const float4* wt4 = (const float4*)wT;
    #pragma unroll
    for (int q=0;q<2;q++){
      int c = tid*2 + q;
      int l = c >> 4, kk = c & 15;
      int swl = (l & 15) ^ (((l>>4)&1) << 2);
      wlds[l][kk ^ swl] = wt4[c];
    }
  }

  const int n = __builtin_amdgcn_readfirstlane(blockIdx.x*8 + wv);  // 0..9999

  // straight-line gather: offsets first (static addresses), then all 32 loads
  const char* ybb = (const char*)yb_in + (uint32_t)(lane*4);
  const uint4* op = (const uint4*)(csrd + (uint32_t)n*32u);
  uint4 o0=op[0], o1=op[1], o2=op[2], o3=op[3];
  uint4 o4=op[4], o5=op[5], o6=op[6], o7=op[7];

  float2 hold = h_in[(size_t)n*HDIM + lane];

  uint32_t g0  = *(const uint32_t*)(ybb+o0.x);
  uint32_t g1  = *(const uint32_t*)(ybb+o0.y);
  uint32_t g2  = *(const uint32_t*)(ybb+o0.z);
  uint32_t g3  = *(const uint32_t*)(ybb+o0.w);
  uint32_t g4  = *(const uint32_t*)(ybb+o1.x);
  uint32_t g5  = *(const uint32_t*)(ybb+o1.y);
  uint32_t g6  = *(const uint32_t*)(ybb+o1.z);
  uint32_t g7  = *(const uint32_t*)(ybb+o1.w);
  uint32_t g8  = *(const uint32_t*)(ybb+o2.x);
  uint32_t g9  = *(const uint32_t*)(ybb+o2.y);
  uint32_t g10 = *(const uint32_t*)(ybb+o2.z);
  uint32_t g11 = *(const uint32_t*)(ybb+o2.w);
  uint32_t g12 = *(const uint32_t*)(ybb+o3.x);
  uint32_t g13 = *(const uint32_t*)(ybb+o3.y);
  uint32_t g14 = *(const uint32_t*)(ybb+o3.z);
  uint32_t g15 = *(const uint32_t*)(ybb+o3.w);
  uint32_t g16 = *(const uint32_t*)(ybb+o4.x);
  uint32_t g17 = *(const uint32_t*)(ybb+o4.y);
  uint32_t g18 = *(const uint32_t*)(ybb+o4.z);
  uint32_t g19 = *(const uint32_t*)(ybb+o4.w);
  uint32_t g20 = *(const uint32_t*)(ybb+o5.x);
  uint32_t g21 = *(const uint32_t*)(ybb+o5.y);
  uint32_t g22 = *(const uint32_t*)(ybb+o5.z);
  uint32_t g23 = *(const uint32_t*)(ybb+o5.w);
  uint32_t g24 = *(const uint32_t*)(ybb+o6.x);
  uint32_t g25 = *(const uint32_t*)(ybb+o6.y);
  uint32_t g26 = *(const uint32_t*)(ybb+o6.z);
  uint32_t g27 = *(const uint32_t*)(ybb+o6.w);
  uint32_t g28 = *(const uint32_t*)(ybb+o7.x);
  uint32_t g29 = *(const uint32_t*)(ybb+o7.y);
  uint32_t g30 = *(const uint32_t*)(ybb+o7.z);
  uint32_t g31 = *(const uint32_t*)(ybb+o7.w);

  float2 A0{0.f,0.f},A1{0.f,0.f},A2{0.f,0.f},A3{0.f,0.f};
  ACC8(A0,A1,A2,A3,g0,g1,g2,g3,g4,g5,g6,g7);
  ACC8(A0,A1,A2,A3,g8,g9,g10,g11,g12,g13,g14,g15);
  ACC8(A0,A1,A2,A3,g16,g17,g18,g19,g20,g21,g22,g23);
  ACC8(A0,A1,A2,A3,g24,g25,g26,g27,g28,g29,g30,g31);

  // general-correctness overflow (deg > 32): never taken for this input
  uint32_t ov = __builtin_amdgcn_readfirstlane(ovc[n]);
  if (ov){
    int beg = __builtin_amdgcn_readfirstlane(row_off[n]);
    const uint4* cp = (const uint4*)(csrb + beg + 32);
    #pragma unroll 1
    for (uint32_t r=0;r<ov;r++){
      GATHER8(cp,r,p0,p1,p2,p3,p4,p5,p6,p7);
      ACC8(A0,A1,A2,A3,p0,p1,p2,p3,p4,p5,p6,p7);
    }
  }

  float s0 = (A0.x+A1.x)+(A2.x+A3.x);
  float s1 = (A0.y+A1.y)+(A2.y+A3.y);

  const float  bias = gcn_b[lane];
  const float2 xrv  = xproj[lane];
  const float2 xzv  = xproj[64+lane];
  const float2 xhv  = xproj[128+lane];
  const float  nd   = norm_d[n], ns = norm_s[n];

  float g0f = fmaf(nd, s0, bias);
  float g1f = fmaf(nd, s1, bias);

  float r0 = sigmoidf_(xrv.x+g0f), r1 = sigmoidf_(xrv.y+g1f);
  float z0 = sigmoidf_(xzv.x+g0f), z1 = sigmoidf_(xzv.y+g1f);
  float t0 = tanhf_(xhv.x+r0*g0f), t1 = tanhf_(xhv.y+r1*g1f);
  float hn0 = hold.x + z0*(t0 - hold.x);
  float hn1 = hold.y + z1*(t1 - hold.y);

  const size_t NH = (size_t)NNODES*HDIM;
  h_out[(size_t)n*HDIM + lane] = make_float2(hn0,hn1);
  size_t idx = (size_t)t*NH + (size_t)n*HDIM + lane;
  __builtin_nontemporal_store(hn0, &out[idx]);                      // b=0 plane
  __builtin_nontemporal_store(hn1, &out[(size_t)TSTEPS*NH + idx]);  // b=1 plane

  hstage[wv][lane] = make_float2(hn0,hn1);
  __syncthreads();   // wlds ready + own hstage visible

  // y_new = h_new @ W (broadcast h + per-lane W column from LDS)
  const int sl = (lane & 15) ^ (((lane>>4)&1) << 2);
  const float4* hp = (const float4*)hstage[wv];
  float y0 = 0.f, y1 = 0.f;
  #pragma unroll
  for (int kk=0;kk<16;kk++){
    float4 w4 = wlds[lane][kk ^ sl];
    float4 ha = hp[2*kk];
    float4 hb = hp[2*kk+1];
    y0 = fmaf(w4.x, ha.x, y0); y1 = fmaf(w4.x, ha.y, y1);
    y0 = fmaf(w4.y, ha.z, y0); y1 = fmaf(w4.y, ha.w, y1);
    y0 = fmaf(w4.z, hb.x, y0); y1 = fmaf(w4.z, hb.y, y1);
    y0 = fmaf(w4.w, hb.z, y0); y1 = fmaf(w4.w, hb.w, y1);
  }
  yb_out[(uint32_t)n*HDIM + lane] = pack_bf16x2(ns*y0, ns*y1);
}

extern "C" void kernel_launch(void* const* d_in, const int* in_sizes, int n_in,
                              void* d_out, int out_size, void* d_ws, size_t ws_size,
                              hipStream_t stream){
  const float* x   = (const float*)d_in[0];
  const int*   src = (const int*)d_in[1];
  const int*   dst = (const int*)d_in[2];
  const float* wr  = (const float*)d_in[3];
  const float* br  = (const float*)d_in[4];
  const float* wz  = (const float*)d_in[5];
  const float* bz  = (const float*)d_in[6];
  const float* wh  = (const float*)d_in[7];
  const float* bh  = (const float*)d_in[8];
  const float* gw  = (const float*)d_in[9];
  const float* gb  = (const float*)d_in[10];
  float* out = (float*)d_out;
  const int E = in_sizes[1];

  char* ws = (char*)d_ws;
  size_t o = 0;
  int*   deg_out = (int*)(ws+o);  o += 10240*4;
  int*   deg_in  = (int*)(ws+o);  o += 10240*4;
  int*   cursor  = (int*)(ws+o);  o += 10240*4;
  int*   row_off = (int*)(ws+o);  o += 10256*4;
  float* norm_s  = (float*)(ws+o); o += 10240*4;
  float* norm_d  = (float*)(ws+o); o += 10240*4;
  const size_t CSRCAP = (size_t)E + 7*NNODES + 16;
  uint32_t* csrb = (uint32_t*)(ws+o);  o += ((CSRCAP*4 + 15) & ~(size_t)15);
  uint32_t* csrd = (uint32_t*)(ws+o);  o += (size_t)NNODES*32*4;   // 1.28 MB dense offsets
  uint32_t* ovc  = (uint32_t*)(ws+o);  o += (size_t)NNODES*4;
  float* xproj   = (float*)(ws+o); o += 512*4;
  float* wT      = (float*)(ws+o); o += 4096*4;
  o = (o + 255) & ~(size_t)255;
  const size_t NHf2 = (size_t)NNODES*HDIM*sizeof(float2);        // 5.12 MB
  const size_t NYB  = (size_t)(NNODES+1)*HDIM*sizeof(uint32_t);  // 2.56 MB (+sentinel)
  uint32_t* yb0 = (uint32_t*)(ws+o); o += NYB;   // yb0,yb1,h0 contiguous -> one memset
  uint32_t* yb1 = (uint32_t*)(ws+o); o += NYB;
  float2*   h0  = (float2*)(ws+o);   o += NHf2;
  float2*   h1  = (float2*)(ws+o);   o += NHf2;  // fully written before first read

  hipMemsetAsync(deg_out, 0, 2*10240*4, stream);
  hipMemsetAsync(yb0, 0, 2*NYB + NHf2, stream);  // zeros yb0, yb1 (sentinels), h0

  int eb = (E+255)/256;
  hist_kernel<<<eb,256,0,stream>>>(src,dst,deg_out,deg_in,E);
  scan_kernel<<<1,256,0,stream>>>(deg_in,deg_out,row_off,cursor,norm_s,norm_d);
  fill_kernel<<<eb,256,0,stream>>>(src,dst,cursor,csrb,E);
  pad_kernel<<<(NNODES+255)/256,256,0,stream>>>(row_off,cursor,csrb);
  dense_kernel<<<(NNODES*32+255)/256,256,0,stream>>>(row_off,csrb,csrd,ovc);
  xproj_kernel<<<1,384,0,stream>>>(x,wr,br,wz,bz,wh,bh,xproj);
  transpose_w_kernel<<<1,256,0,stream>>>(gw,wT);

  float2* hin = h0;  float2* hout = h1;
  uint32_t* ybin = yb0; uint32_t* ybout = yb1;
  for (int t=0;t<TSTEPS;t++){
    step_kernel<<<1250,512,0,stream>>>(hin,hout,ybin,ybout,out,t,csrd,ovc,
                                       row_off,csrb,norm_d,norm_s,wT,gb,
                                       (const float2*)xproj);
    float2* tf = hin; hin = hout; hout = tf;
    uint32_t* tb = ybin; ybin = ybout; ybout = tb;
  }
}